// Round 5
// baseline (488.942 us; speedup 1.0000x reference)
//
#include <hip/hip_runtime.h>

// GAT, 2 layers, H=2 heads, D=C=128, concat=False (head mean), L2 normalize after each layer.
// Float tensors: fp32 OR bf16 (runtime-probed). edge_index: int32 OR int64 (runtime-probed).
// Output written in the probed float dtype. Internal h-matrix always bf16 (MFMA).

using short8  = __attribute__((ext_vector_type(8))) short;
using float4v = __attribute__((ext_vector_type(4))) float;

static __device__ __forceinline__ float bf2f(unsigned int u16) {
    union { unsigned int i; float f; } v; v.i = u16 << 16; return v.f;
}
static __device__ __forceinline__ float bflo(unsigned int p){  // low bf16 -> f32
    union { unsigned int i; float f; } v; v.i = p << 16; return v.f;
}
static __device__ __forceinline__ float bfhi(unsigned int p){  // high bf16 -> f32
    union { unsigned int i; float f; } v; v.i = p & 0xffff0000u; return v.f;
}
static __device__ __forceinline__ unsigned short f2bf(float f) {
    union { float f; unsigned int i; } v; v.f = f;
    unsigned int x = v.i;
    x += 0x7fffu + ((x >> 16) & 1u);   // RNE
    return (unsigned short)(x >> 16);
}
static __device__ __forceinline__ float leaky(float x){ return x > 0.f ? x : 0.2f * x; }

// ---------------- probe dtypes + zero cursor (fused) ----------------
// flags[0]=1 iff x is fp32; flags[1]=1 iff edge_index is int64.
__global__ __launch_bounds__(256) void k_probe_zero(const unsigned int* __restrict__ xw,
                                                    const int* __restrict__ ei,
                                                    int* __restrict__ flags,
                                                    int* __restrict__ cursor, int N) {
    int i = blockIdx.x * 256 + threadIdx.x;
    if (i < N) cursor[i] = 0;
    if (blockIdx.x == 0) {
        __shared__ int insane, oddnz;
        int t = threadIdx.x;
        if (t == 0) { insane = 0; oddnz = 0; }
        __syncthreads();
        unsigned int w = xw[t];
        if (((w >> 7) & 0xFFu) >= 154u) atomicOr(&insane, 1);
        if (ei[2 * t + 1] != 0) atomicOr(&oddnz, 1);
        __syncthreads();
        if (t == 0) { flags[0] = insane ? 1 : 0; flags[1] = oddnz ? 0 : 1; }
    }
}

// ---------------- W -> WT (bf16): WT[l][n][k] = W[l][k][n] ----------------
__global__ __launch_bounds__(256) void k_transpose(const void* __restrict__ W,
                                                   unsigned short* __restrict__ WT,
                                                   const int* __restrict__ flags) {
    int fx = flags[0];
    int idx = blockIdx.x * 256 + threadIdx.x;      // 0 .. 2*128*256-1
    int layer = idx >> 15;
    int rem = idx & 32767;
    int k = rem >> 8, n = rem & 255;
    int srci = layer * 32768 + k * 256 + n;
    unsigned short v;
    if (fx) v = f2bf(((const float*)W)[srci]);
    else    v = ((const unsigned short*)W)[srci];
    WT[layer * 32768 + n * 128 + k] = v;
}

// ---------------- fused GEMM + alpha: Hb = X@W (bf16 out), as_/ad_ = (h . att) per head ----
// one block per 16-row tile; wave w computes col tiles [4w,4w+4) (single head per wave).
__global__ __launch_bounds__(256) void k_gemm_alpha(const void* __restrict__ X,
                                                    const unsigned short* __restrict__ WT,
                                                    const void* __restrict__ atts,
                                                    const void* __restrict__ attd,
                                                    int layer,
                                                    unsigned short* __restrict__ Hb,
                                                    float* __restrict__ as_, float* __restrict__ ad_,
                                                    int N, const int* __restrict__ flags) {
    __shared__ float lds_s[4][16], lds_d[4][16];
    int fx = flags[0];
    int mt = blockIdx.x;
    int wave = threadIdx.x >> 6;
    int lane = threadIdx.x & 63;
    int r16 = lane & 15, quad = lane >> 4;
    int m0 = mt << 4;
    int arow = m0 + r16; if (arow >= N) arow = N - 1;
    short8 a[4];
    if (fx) {
        const float* Xf = (const float*)X;
#pragma unroll
        for (int kk = 0; kk < 4; kk++) {
            const float4v* pv = (const float4v*)(Xf + (size_t)arow * 128 + kk * 32 + quad * 8);
            float4v lo = pv[0], hi = pv[1];
            short8 t;
            t[0] = (short)f2bf(lo[0]); t[1] = (short)f2bf(lo[1]);
            t[2] = (short)f2bf(lo[2]); t[3] = (short)f2bf(lo[3]);
            t[4] = (short)f2bf(hi[0]); t[5] = (short)f2bf(hi[1]);
            t[6] = (short)f2bf(hi[2]); t[7] = (short)f2bf(hi[3]);
            a[kk] = t;
        }
    } else {
        const unsigned short* Xh = (const unsigned short*)X;
#pragma unroll
        for (int kk = 0; kk < 4; kk++)
            a[kk] = *(const short8*)(Xh + (size_t)arow * 128 + kk * 32 + quad * 8);
    }
    int head = wave >> 1;
    float ps[4] = {0.f, 0.f, 0.f, 0.f}, pd[4] = {0.f, 0.f, 0.f, 0.f};
#pragma unroll
    for (int nn = 0; nn < 4; nn++) {
        int nt = wave * 4 + nn;
        float4v acc = {0.f, 0.f, 0.f, 0.f};
#pragma unroll
        for (int kk = 0; kk < 4; kk++) {
            short8 b = *(const short8*)(WT + (nt * 16 + r16) * 128 + kk * 32 + quad * 8);
            acc = __builtin_amdgcn_mfma_f32_16x16x32_bf16(a[kk], b, acc, 0, 0, 0);
        }
        int col = nt * 16 + r16;
        int c = col & 127;
        float sa, da;
        if (fx) {
            sa = ((const float*)atts)[layer * 256 + head * 128 + c];
            da = ((const float*)attd)[layer * 256 + head * 128 + c];
        } else {
            sa = bf2f(((const unsigned short*)atts)[layer * 256 + head * 128 + c]);
            da = bf2f(((const unsigned short*)attd)[layer * 256 + head * 128 + c]);
        }
#pragma unroll
        for (int r = 0; r < 4; r++) {
            int row = m0 + quad * 4 + r;           // C/D: col=lane&15, row=quad*4+reg  [m89]
            if (row < N) Hb[(size_t)row * 256 + col] = f2bf(acc[r]);
            ps[r] += acc[r] * sa;
            pd[r] += acc[r] * da;
        }
    }
    // reduce partial dots over the 16 cols held by lanes r16 (within each quad group)
#pragma unroll
    for (int m = 1; m < 16; m <<= 1) {
#pragma unroll
        for (int r = 0; r < 4; r++) {
            ps[r] += __shfl_xor(ps[r], m);
            pd[r] += __shfl_xor(pd[r], m);
        }
    }
    if (r16 == 0) {
#pragma unroll
        for (int r = 0; r < 4; r++) {
            lds_s[wave][quad * 4 + r] = ps[r];
            lds_d[wave][quad * 4 + r] = pd[r];
        }
    }
    __syncthreads();
    if (threadIdx.x < 16) {
        int row = m0 + threadIdx.x;
        if (row < N) {
            float2 sv = { lds_s[0][threadIdx.x] + lds_s[1][threadIdx.x],
                          lds_s[2][threadIdx.x] + lds_s[3][threadIdx.x] };
            float2 dv = { lds_d[0][threadIdx.x] + lds_d[1][threadIdx.x],
                          lds_d[2][threadIdx.x] + lds_d[3][threadIdx.x] };
            *(float2*)(as_ + 2 * row) = sv;   // [head0, head1]
            *(float2*)(ad_ + 2 * row) = dv;
        }
    }
}

// ---------------- CSR build ----------------
static __device__ __forceinline__ int edge_dst(const int* ei, int E, int i, int is64) {
    return is64 ? ei[2 * E + 2 * i] : ei[E + i];
}
static __device__ __forceinline__ int edge_src(const int* ei, int E, int i, int is64) {
    return is64 ? ei[2 * i] : ei[i];
}

__global__ __launch_bounds__(256) void k_count(const int* __restrict__ ei, int E, int N,
                                               const int* __restrict__ flags, int* deg) {
    int i = blockIdx.x * 256 + threadIdx.x;
    if (i >= E + N) return;
    int dst;
    if (i < E) { dst = edge_dst(ei, E, i, flags[1]); if ((unsigned)dst >= (unsigned)N) dst = 0; }
    else dst = i - E;   // self loops appended
    atomicAdd(&deg[dst], 1);
}

// single-block full exclusive scan: deg (=cursor) -> rowptr + cursor copy
__global__ __launch_bounds__(1024) void k_scan(const int* __restrict__ deg,
                                               int* __restrict__ rowptr,
                                               int* __restrict__ cursor, int N) {
    __shared__ int tsum[1024];
    int t = threadIdx.x;
    int chunk = (N + 1023) >> 10;
    int lo = t * chunk;
    int hi = lo + chunk; if (hi > N) hi = N;
    int sum = 0;
    for (int i = lo; i < hi; i++) sum += deg[i];
    tsum[t] = sum; __syncthreads();
    int x = sum;
    for (int off = 1; off < 1024; off <<= 1) {
        int add = (t >= off) ? tsum[t - off] : 0;
        __syncthreads();
        x += add; tsum[t] = x;
        __syncthreads();
    }
    int run = x - sum;   // exclusive offset of this chunk
    for (int i = lo; i < hi; i++) {
        int d = deg[i];          // read before cursor overwrite (same array, same element)
        rowptr[i] = run;
        cursor[i] = run;
        run += d;
    }
    if (t == 1023) rowptr[N] = run;  // t=1023's run == grand total even when its chunk is empty
}

__global__ __launch_bounds__(256) void k_scatter(const int* __restrict__ ei, int E, int N,
                                                 const int* __restrict__ flags,
                                                 int* __restrict__ cursor, int* __restrict__ csr) {
    int i = blockIdx.x * 256 + threadIdx.x;
    if (i >= E + N) return;
    int src, dst;
    if (i < E) {
        int is64 = flags[1];
        src = edge_src(ei, E, i, is64);
        dst = edge_dst(ei, E, i, is64);
        if ((unsigned)src >= (unsigned)N) src = 0;
        if ((unsigned)dst >= (unsigned)N) dst = 0;
    } else src = dst = i - E;
    int pos = atomicAdd(&cursor[dst], 1);
    csr[pos] = src;
}

// ---------------- per-dst softmax + aggregation + head-mean + bias + L2 norm ----------------
// one wave per node; fast path (deg<=64): single fused sweep; 4 lane-groups of 16 gather
// one edge each (2x dwordx4/lane, 512B/edge), 4 edges in flight.
static __device__ __forceinline__ void acc8(float* A, float w, uint4 q) {
    A[0] += w * bflo(q.x); A[1] += w * bfhi(q.x);
    A[2] += w * bflo(q.y); A[3] += w * bfhi(q.y);
    A[4] += w * bflo(q.z); A[5] += w * bfhi(q.z);
    A[6] += w * bflo(q.w); A[7] += w * bfhi(q.w);
}

__global__ __launch_bounds__(256) void k_aggregate(const unsigned short* __restrict__ Hb,
                                                   const float* __restrict__ as_, const float* __restrict__ ad_,
                                                   const int* __restrict__ rowptr, const int* __restrict__ csr,
                                                   const void* __restrict__ bias, int layer,
                                                   const int* __restrict__ flags,
                                                   void* __restrict__ outp, int N, int EL) {
    int fx = flags[0];
    int n = blockIdx.x * 4 + (threadIdx.x >> 6);
    if (n >= N) return;
    int lane = threadIdx.x & 63;
    int g = lane >> 4;       // group 0..3
    int gl = lane & 15;      // lane in group; owns channels [gl*8, gl*8+8) of each head
    int start = rowptr[n], end = rowptr[n + 1];
    if (start < 0) start = 0;
    if (end > EL) end = EL;
    if (end < start) end = start;
    float2 adv = *(const float2*)(ad_ + 2 * n);
    float ad0 = adv.x, ad1 = adv.y;

    float acc0[8] = {0,0,0,0,0,0,0,0}, acc1[8] = {0,0,0,0,0,0,0,0};
    float z0, z1;
    int deg = end - start;

    if (deg <= 64) {
        // ---- fast path: one sweep ----
        int i = start + lane;
        bool act = i < end;
        int s = 0; float l0 = -1e30f, l1 = -1e30f;
        if (act) {
            s = csr[i]; if ((unsigned)s >= (unsigned)N) s = 0;
            float2 av = *(const float2*)(as_ + 2 * s);
            l0 = leaky(av.x + ad0); l1 = leaky(av.y + ad1);
        }
        float m0 = l0, m1 = l1;
#pragma unroll
        for (int m = 1; m < 64; m <<= 1) { m0 = fmaxf(m0, __shfl_xor(m0, m)); m1 = fmaxf(m1, __shfl_xor(m1, m)); }
        float w0 = act ? __expf(l0 - m0) : 0.f;
        float w1 = act ? __expf(l1 - m1) : 0.f;
        z0 = w0; z1 = w1;
#pragma unroll
        for (int m = 1; m < 64; m <<= 1) { z0 += __shfl_xor(z0, m); z1 += __shfl_xor(z1, m); }
#pragma unroll 2
        for (int j = 0; 4 * j < deg; j++) {
            int e = 4 * j + g;
            int sq    = __shfl(s, e);
            float wq0 = __shfl(w0, e);
            float wq1 = __shfl(w1, e);
            if (e < deg) {
                const unsigned short* row = Hb + ((size_t)sq << 8);
                uint4 q0 = *(const uint4*)(row + gl * 8);
                uint4 q1 = *(const uint4*)(row + 128 + gl * 8);
                acc8(acc0, wq0, q0);
                acc8(acc1, wq1, q1);
            }
        }
    } else {
        // ---- slow path (deg > 64): two-pass ----
        float m0 = -1e30f, m1 = -1e30f;
        for (int i = start + lane; i < end; i += 64) {
            int s = csr[i]; if ((unsigned)s >= (unsigned)N) s = 0;
            float2 av = *(const float2*)(as_ + 2 * s);
            m0 = fmaxf(m0, leaky(av.x + ad0));
            m1 = fmaxf(m1, leaky(av.y + ad1));
        }
#pragma unroll
        for (int m = 1; m < 64; m <<= 1) { m0 = fmaxf(m0, __shfl_xor(m0, m)); m1 = fmaxf(m1, __shfl_xor(m1, m)); }
        z0 = 0.f; z1 = 0.f;
        for (int t = start; t < end; t += 64) {
            int i = t + lane;
            int s = 0; float w0 = 0.f, w1 = 0.f;
            if (i < end) {
                s = csr[i]; if ((unsigned)s >= (unsigned)N) s = 0;
                float2 av = *(const float2*)(as_ + 2 * s);
                w0 = __expf(leaky(av.x + ad0) - m0);
                w1 = __expf(leaky(av.y + ad1) - m1);
                z0 += w0; z1 += w1;
            }
            int cnt = end - t; if (cnt > 64) cnt = 64;
            for (int j = 0; 4 * j < cnt; j++) {
                int e = 4 * j + g;
                int sq    = __shfl(s, e);
                float wq0 = __shfl(w0, e);
                float wq1 = __shfl(w1, e);
                if (e < cnt) {
                    const unsigned short* row = Hb + ((size_t)sq << 8);
                    uint4 q0 = *(const uint4*)(row + gl * 8);
                    uint4 q1 = *(const uint4*)(row + 128 + gl * 8);
                    acc8(acc0, wq0, q0);
                    acc8(acc1, wq1, q1);
                }
            }
        }
#pragma unroll
        for (int m = 1; m < 64; m <<= 1) { z0 += __shfl_xor(z0, m); z1 += __shfl_xor(z1, m); }
    }

    float inv0 = 1.f / (z0 + 1e-16f), inv1 = 1.f / (z1 + 1e-16f);
    // combine the 4 groups' partial accumulators
#pragma unroll
    for (int k = 0; k < 8; k++) {
        acc0[k] += __shfl_xor(acc0[k], 16); acc0[k] += __shfl_xor(acc0[k], 32);
        acc1[k] += __shfl_xor(acc1[k], 16); acc1[k] += __shfl_xor(acc1[k], 32);
    }

    // head mean + bias (channels gl*8 .. gl*8+8)
    float v[8];
    if (fx) {
        const float* bf = (const float*)bias + layer * 128 + gl * 8;
#pragma unroll
        for (int k = 0; k < 8; k++) v[k] = 0.5f * (acc0[k] * inv0 + acc1[k] * inv1) + bf[k];
    } else {
        const unsigned short* bh = (const unsigned short*)bias + layer * 128 + gl * 8;
        uint4 bv = *(const uint4*)bh;
        float bfv[8] = { bflo(bv.x), bfhi(bv.x), bflo(bv.y), bfhi(bv.y),
                         bflo(bv.z), bfhi(bv.z), bflo(bv.w), bfhi(bv.w) };
#pragma unroll
        for (int k = 0; k < 8; k++) v[k] = 0.5f * (acc0[k] * inv0 + acc1[k] * inv1) + bfv[k];
    }

    // L2 normalize over 128 channels (reduce within 16-lane group)
    float ss = 0.f;
#pragma unroll
    for (int k = 0; k < 8; k++) ss += v[k] * v[k];
#pragma unroll
    for (int m = 1; m < 16; m <<= 1) ss += __shfl_xor(ss, m);
    float inv = 1.f / fmaxf(sqrtf(ss), 1e-12f);

    if (lane < 16) {   // group 0 writes; channels gl*8..gl*8+8
        if (fx) {
            float* op = (float*)outp + (size_t)n * 128 + gl * 8;
            float4 o0 = { v[0] * inv, v[1] * inv, v[2] * inv, v[3] * inv };
            float4 o1 = { v[4] * inv, v[5] * inv, v[6] * inv, v[7] * inv };
            *(float4*)op = o0;
            *(float4*)(op + 4) = o1;
        } else {
            unsigned short* op = (unsigned short*)outp + (size_t)n * 128 + gl * 8;
            uint4 pk;
            pk.x = (unsigned int)f2bf(v[0] * inv) | ((unsigned int)f2bf(v[1] * inv) << 16);
            pk.y = (unsigned int)f2bf(v[2] * inv) | ((unsigned int)f2bf(v[3] * inv) << 16);
            pk.z = (unsigned int)f2bf(v[4] * inv) | ((unsigned int)f2bf(v[5] * inv) << 16);
            pk.w = (unsigned int)f2bf(v[6] * inv) | ((unsigned int)f2bf(v[7] * inv) << 16);
            *(uint4*)op = pk;
        }
    }
}

extern "C" void kernel_launch(void* const* d_in, const int* in_sizes, int n_in,
                              void* d_out, int out_size, void* d_ws, size_t ws_size,
                              hipStream_t stream) {
    const void* x    = d_in[0];               // [N,128] fp32 or bf16
    const int*  ei   = (const int*)d_in[1];   // [2,E] int32 or int64
    const void* W    = d_in[2];               // [2,128,256]
    const void* atts = d_in[3];               // [2,2,128]
    const void* attd = d_in[4];               // [2,2,128]
    const void* bias = d_in[5];               // [2,128]

    int N = in_sizes[0] / 128;
    int E = in_sizes[1] / 2;
    int EL = E + N;

    char* p = (char*)d_ws;
    auto alloc = [&](size_t bytes) -> char* {
        char* q = p; p += (bytes + 255) & ~(size_t)255; return q;
    };
    int* flags   = (int*)alloc(256);
    int* rowptr  = (int*)alloc((size_t)(N + 1) * 4);
    int* cursor  = (int*)alloc((size_t)N * 4);
    float* as_   = (float*)alloc((size_t)N * 2 * 4);
    float* ad_   = (float*)alloc((size_t)N * 2 * 4);
    unsigned short* wt = (unsigned short*)alloc(2 * 256 * 128 * 2);
    int* csr     = (int*)alloc((size_t)EL * 4);
    unsigned short* hbuf = (unsigned short*)alloc((size_t)N * 256 * 2);   // 25.6 MB, last

    k_probe_zero<<<(N + 255) / 256, 256, 0, stream>>>((const unsigned int*)x, ei, flags, cursor, N);
    k_count<<<(EL + 255) / 256, 256, 0, stream>>>(ei, E, N, flags, cursor);
    k_scan<<<1, 1024, 0, stream>>>(cursor, rowptr, cursor, N);
    k_scatter<<<(EL + 255) / 256, 256, 0, stream>>>(ei, E, N, flags, cursor, csr);
    k_transpose<<<256, 256, 0, stream>>>(W, wt, flags);

    int mtiles = (N + 15) / 16;
    for (int l = 0; l < 2; l++) {
        const void* xin = (l == 0) ? x : (const void*)d_out;  // layer 1 reads layer-0 output
        k_gemm_alpha<<<mtiles, 256, 0, stream>>>(xin, wt + l * 32768, atts, attd, l,
                                                 hbuf, as_, ad_, N, flags);
        k_aggregate<<<(N + 3) / 4, 256, 0, stream>>>(hbuf, as_, ad_, rowptr, csr, bias, l, flags,
                                                     d_out, N, EL);
    }
}

// Round 6
// 388.839 us; speedup vs baseline: 1.2574x; 1.2574x over previous
//
#include <hip/hip_runtime.h>

// GAT, 2 layers, H=2 heads, D=C=128, concat=False (head mean), L2 normalize after each layer.
// Float tensors: fp32 OR bf16 (runtime-probed). edge_index: int32 OR int64 (runtime-probed).
// Output written in the probed float dtype. Internal h-matrix always bf16 (MFMA).

using short8  = __attribute__((ext_vector_type(8))) short;
using float4v = __attribute__((ext_vector_type(4))) float;

static __device__ __forceinline__ float bf2f(unsigned int u16) {
    union { unsigned int i; float f; } v; v.i = u16 << 16; return v.f;
}
static __device__ __forceinline__ float bflo(unsigned int p){  // low bf16 -> f32
    union { unsigned int i; float f; } v; v.i = p << 16; return v.f;
}
static __device__ __forceinline__ float bfhi(unsigned int p){  // high bf16 -> f32
    union { unsigned int i; float f; } v; v.i = p & 0xffff0000u; return v.f;
}
static __device__ __forceinline__ unsigned short f2bf(float f) {
    union { float f; unsigned int i; } v; v.f = f;
    unsigned int x = v.i;
    x += 0x7fffu + ((x >> 16) & 1u);   // RNE
    return (unsigned short)(x >> 16);
}
static __device__ __forceinline__ float leaky(float x){ return x > 0.f ? x : 0.2f * x; }

// ---------------- probe dtypes + zero cursor (fused) ----------------
// flags[0]=1 iff x is fp32; flags[1]=1 iff edge_index is int64.
__global__ __launch_bounds__(256) void k_probe_zero(const unsigned int* __restrict__ xw,
                                                    const int* __restrict__ ei,
                                                    int* __restrict__ flags,
                                                    int* __restrict__ cursor, int N) {
    int i = blockIdx.x * 256 + threadIdx.x;
    if (i < N) cursor[i] = 0;
    if (blockIdx.x == 0) {
        __shared__ int insane, oddnz;
        int t = threadIdx.x;
        if (t == 0) { insane = 0; oddnz = 0; }
        __syncthreads();
        unsigned int w = xw[t];
        if (((w >> 7) & 0xFFu) >= 154u) atomicOr(&insane, 1);
        if (ei[2 * t + 1] != 0) atomicOr(&oddnz, 1);
        __syncthreads();
        if (t == 0) { flags[0] = insane ? 1 : 0; flags[1] = oddnz ? 0 : 1; }
    }
}

// ---------------- W -> WT (bf16): WT[l][n][k] = W[l][k][n] ----------------
__global__ __launch_bounds__(256) void k_transpose(const void* __restrict__ W,
                                                   unsigned short* __restrict__ WT,
                                                   const int* __restrict__ flags) {
    int fx = flags[0];
    int idx = blockIdx.x * 256 + threadIdx.x;      // 0 .. 2*128*256-1
    int layer = idx >> 15;
    int rem = idx & 32767;
    int k = rem >> 8, n = rem & 255;
    int srci = layer * 32768 + k * 256 + n;
    unsigned short v;
    if (fx) v = f2bf(((const float*)W)[srci]);
    else    v = ((const unsigned short*)W)[srci];
    WT[layer * 32768 + n * 128 + k] = v;
}

// ---------------- fused GEMM + alpha: Hb = X@W (bf16 out), as_/ad_ = (h . att) per head ----
// one block per 16-row tile; wave w computes col tiles [4w,4w+4) (single head per wave).
__global__ __launch_bounds__(256) void k_gemm_alpha(const void* __restrict__ X,
                                                    const unsigned short* __restrict__ WT,
                                                    const void* __restrict__ atts,
                                                    const void* __restrict__ attd,
                                                    int layer,
                                                    unsigned short* __restrict__ Hb,
                                                    float* __restrict__ as_, float* __restrict__ ad_,
                                                    int N, const int* __restrict__ flags) {
    __shared__ float lds_s[4][16], lds_d[4][16];
    int fx = flags[0];
    int mt = blockIdx.x;
    int wave = threadIdx.x >> 6;
    int lane = threadIdx.x & 63;
    int r16 = lane & 15, quad = lane >> 4;
    int m0 = mt << 4;
    int arow = m0 + r16; if (arow >= N) arow = N - 1;
    short8 a[4];
    if (fx) {
        const float* Xf = (const float*)X;
#pragma unroll
        for (int kk = 0; kk < 4; kk++) {
            const float4v* pv = (const float4v*)(Xf + (size_t)arow * 128 + kk * 32 + quad * 8);
            float4v lo = pv[0], hi = pv[1];
            short8 t;
            t[0] = (short)f2bf(lo[0]); t[1] = (short)f2bf(lo[1]);
            t[2] = (short)f2bf(lo[2]); t[3] = (short)f2bf(lo[3]);
            t[4] = (short)f2bf(hi[0]); t[5] = (short)f2bf(hi[1]);
            t[6] = (short)f2bf(hi[2]); t[7] = (short)f2bf(hi[3]);
            a[kk] = t;
        }
    } else {
        const unsigned short* Xh = (const unsigned short*)X;
#pragma unroll
        for (int kk = 0; kk < 4; kk++)
            a[kk] = *(const short8*)(Xh + (size_t)arow * 128 + kk * 32 + quad * 8);
    }
    int head = wave >> 1;
    float ps[4] = {0.f, 0.f, 0.f, 0.f}, pd[4] = {0.f, 0.f, 0.f, 0.f};
#pragma unroll
    for (int nn = 0; nn < 4; nn++) {
        int nt = wave * 4 + nn;
        float4v acc = {0.f, 0.f, 0.f, 0.f};
#pragma unroll
        for (int kk = 0; kk < 4; kk++) {
            short8 b = *(const short8*)(WT + (nt * 16 + r16) * 128 + kk * 32 + quad * 8);
            acc = __builtin_amdgcn_mfma_f32_16x16x32_bf16(a[kk], b, acc, 0, 0, 0);
        }
        int col = nt * 16 + r16;
        int c = col & 127;
        float sa, da;
        if (fx) {
            sa = ((const float*)atts)[layer * 256 + head * 128 + c];
            da = ((const float*)attd)[layer * 256 + head * 128 + c];
        } else {
            sa = bf2f(((const unsigned short*)atts)[layer * 256 + head * 128 + c]);
            da = bf2f(((const unsigned short*)attd)[layer * 256 + head * 128 + c]);
        }
#pragma unroll
        for (int r = 0; r < 4; r++) {
            int row = m0 + quad * 4 + r;           // C/D: col=lane&15, row=quad*4+reg  [m89]
            if (row < N) Hb[(size_t)row * 256 + col] = f2bf(acc[r]);
            ps[r] += acc[r] * sa;
            pd[r] += acc[r] * da;
        }
    }
    // reduce partial dots over the 16 cols held by lanes r16 (within each quad group)
#pragma unroll
    for (int m = 1; m < 16; m <<= 1) {
#pragma unroll
        for (int r = 0; r < 4; r++) {
            ps[r] += __shfl_xor(ps[r], m);
            pd[r] += __shfl_xor(pd[r], m);
        }
    }
    if (r16 == 0) {
#pragma unroll
        for (int r = 0; r < 4; r++) {
            lds_s[wave][quad * 4 + r] = ps[r];
            lds_d[wave][quad * 4 + r] = pd[r];
        }
    }
    __syncthreads();
    if (threadIdx.x < 16) {
        int row = m0 + threadIdx.x;
        if (row < N) {
            float2 sv = { lds_s[0][threadIdx.x] + lds_s[1][threadIdx.x],
                          lds_s[2][threadIdx.x] + lds_s[3][threadIdx.x] };
            float2 dv = { lds_d[0][threadIdx.x] + lds_d[1][threadIdx.x],
                          lds_d[2][threadIdx.x] + lds_d[3][threadIdx.x] };
            *(float2*)(as_ + 2 * row) = sv;   // [head0, head1]
            *(float2*)(ad_ + 2 * row) = dv;
        }
    }
}

// ---------------- CSR build ----------------
static __device__ __forceinline__ int edge_dst(const int* ei, int E, int i, int is64) {
    return is64 ? ei[2 * E + 2 * i] : ei[E + i];
}
static __device__ __forceinline__ int edge_src(const int* ei, int E, int i, int is64) {
    return is64 ? ei[2 * i] : ei[i];
}

__global__ __launch_bounds__(256) void k_count(const int* __restrict__ ei, int E, int N,
                                               const int* __restrict__ flags, int* deg) {
    int i = blockIdx.x * 256 + threadIdx.x;
    if (i >= E + N) return;
    int dst;
    if (i < E) { dst = edge_dst(ei, E, i, flags[1]); if ((unsigned)dst >= (unsigned)N) dst = 0; }
    else dst = i - E;   // self loops appended
    atomicAdd(&deg[dst], 1);
}

// multi-block scan chain (R3-proven): scan1 per-block ladder -> scan2 block sums -> scan3 add base
__global__ __launch_bounds__(1024) void k_scan1(const int* __restrict__ deg, int* __restrict__ excl,
                                                int* __restrict__ bsum, int n) {
    __shared__ int buf[1024];
    int t = threadIdx.x;
    int i = blockIdx.x * 1024 + t;
    int v = (i < n) ? deg[i] : 0;
    int x = v; buf[t] = v; __syncthreads();
    for (int off = 1; off < 1024; off <<= 1) {
        int add = (t >= off) ? buf[t - off] : 0;
        __syncthreads();
        x += add; buf[t] = x;
        __syncthreads();
    }
    if (i < n) excl[i] = x - v;
    if (t == 1023) bsum[blockIdx.x] = x;
}

__global__ __launch_bounds__(256) void k_scan2(int* bsum, int nb) {
    __shared__ int buf[256];
    int t = threadIdx.x;
    int v = (t < nb) ? bsum[t] : 0;
    int x = v; buf[t] = v; __syncthreads();
    for (int off = 1; off < 256; off <<= 1) {
        int add = (t >= off) ? buf[t - off] : 0;
        __syncthreads();
        x += add; buf[t] = x;
        __syncthreads();
    }
    if (t < nb) bsum[t] = x - v;
    if (t == nb - 1) bsum[nb] = x;   // grand total
}

// rowptr[i] += base; cursor[i] = rowptr[i]  (k_cursor folded in)
__global__ __launch_bounds__(256) void k_scan3(int* __restrict__ rowptr, const int* __restrict__ bsum,
                                               int* __restrict__ cursor, int N) {
    int i = blockIdx.x * 256 + threadIdx.x;
    if (i < N) {
        int r = rowptr[i] + bsum[i >> 10];
        rowptr[i] = r;
        cursor[i] = r;
    } else if (i == N) {
        rowptr[N] = bsum[(N + 1023) >> 10];
    }
}

__global__ __launch_bounds__(256) void k_scatter(const int* __restrict__ ei, int E, int N,
                                                 const int* __restrict__ flags,
                                                 int* __restrict__ cursor, int* __restrict__ csr) {
    int i = blockIdx.x * 256 + threadIdx.x;
    if (i >= E + N) return;
    int src, dst;
    if (i < E) {
        int is64 = flags[1];
        src = edge_src(ei, E, i, is64);
        dst = edge_dst(ei, E, i, is64);
        if ((unsigned)src >= (unsigned)N) src = 0;
        if ((unsigned)dst >= (unsigned)N) dst = 0;
    } else src = dst = i - E;
    int pos = atomicAdd(&cursor[dst], 1);
    csr[pos] = src;
}

// ---------------- per-dst softmax + aggregation + head-mean + bias + L2 norm ----------------
// one wave per node; fast path (deg<=64): single fused sweep; 4 lane-groups of 16 gather
// one edge each (2x dwordx4/lane, 512B/edge), 4 edges in flight.
static __device__ __forceinline__ void acc8(float* A, float w, uint4 q) {
    A[0] += w * bflo(q.x); A[1] += w * bfhi(q.x);
    A[2] += w * bflo(q.y); A[3] += w * bfhi(q.y);
    A[4] += w * bflo(q.z); A[5] += w * bfhi(q.z);
    A[6] += w * bflo(q.w); A[7] += w * bfhi(q.w);
}

__global__ __launch_bounds__(256) void k_aggregate(const unsigned short* __restrict__ Hb,
                                                   const float* __restrict__ as_, const float* __restrict__ ad_,
                                                   const int* __restrict__ rowptr, const int* __restrict__ csr,
                                                   const void* __restrict__ bias, int layer,
                                                   const int* __restrict__ flags,
                                                   void* __restrict__ outp, int N, int EL) {
    int fx = flags[0];
    int n = blockIdx.x * 4 + (threadIdx.x >> 6);
    if (n >= N) return;
    int lane = threadIdx.x & 63;
    int g = lane >> 4;       // group 0..3
    int gl = lane & 15;      // lane in group; owns channels [gl*8, gl*8+8) of each head
    int start = rowptr[n], end = rowptr[n + 1];
    if (start < 0) start = 0;
    if (end > EL) end = EL;
    if (end < start) end = start;
    float2 adv = *(const float2*)(ad_ + 2 * n);
    float ad0 = adv.x, ad1 = adv.y;

    float acc0[8] = {0,0,0,0,0,0,0,0}, acc1[8] = {0,0,0,0,0,0,0,0};
    float z0, z1;
    int deg = end - start;

    if (deg <= 64) {
        // ---- fast path: one sweep ----
        int i = start + lane;
        bool act = i < end;
        int s = 0; float l0 = -1e30f, l1 = -1e30f;
        if (act) {
            s = csr[i]; if ((unsigned)s >= (unsigned)N) s = 0;
            float2 av = *(const float2*)(as_ + 2 * s);
            l0 = leaky(av.x + ad0); l1 = leaky(av.y + ad1);
        }
        float m0 = l0, m1 = l1;
#pragma unroll
        for (int m = 1; m < 64; m <<= 1) { m0 = fmaxf(m0, __shfl_xor(m0, m)); m1 = fmaxf(m1, __shfl_xor(m1, m)); }
        float w0 = act ? __expf(l0 - m0) : 0.f;
        float w1 = act ? __expf(l1 - m1) : 0.f;
        z0 = w0; z1 = w1;
#pragma unroll
        for (int m = 1; m < 64; m <<= 1) { z0 += __shfl_xor(z0, m); z1 += __shfl_xor(z1, m); }
#pragma unroll 2
        for (int j = 0; 4 * j < deg; j++) {
            int e = 4 * j + g;
            int sq    = __shfl(s, e);
            float wq0 = __shfl(w0, e);
            float wq1 = __shfl(w1, e);
            if (e < deg) {
                const unsigned short* row = Hb + ((size_t)sq << 8);
                uint4 q0 = *(const uint4*)(row + gl * 8);
                uint4 q1 = *(const uint4*)(row + 128 + gl * 8);
                acc8(acc0, wq0, q0);
                acc8(acc1, wq1, q1);
            }
        }
    } else {
        // ---- slow path (deg > 64): two-pass ----
        float m0 = -1e30f, m1 = -1e30f;
        for (int i = start + lane; i < end; i += 64) {
            int s = csr[i]; if ((unsigned)s >= (unsigned)N) s = 0;
            float2 av = *(const float2*)(as_ + 2 * s);
            m0 = fmaxf(m0, leaky(av.x + ad0));
            m1 = fmaxf(m1, leaky(av.y + ad1));
        }
#pragma unroll
        for (int m = 1; m < 64; m <<= 1) { m0 = fmaxf(m0, __shfl_xor(m0, m)); m1 = fmaxf(m1, __shfl_xor(m1, m)); }
        z0 = 0.f; z1 = 0.f;
        for (int t = start; t < end; t += 64) {
            int i = t + lane;
            int s = 0; float w0 = 0.f, w1 = 0.f;
            if (i < end) {
                s = csr[i]; if ((unsigned)s >= (unsigned)N) s = 0;
                float2 av = *(const float2*)(as_ + 2 * s);
                w0 = __expf(leaky(av.x + ad0) - m0);
                w1 = __expf(leaky(av.y + ad1) - m1);
                z0 += w0; z1 += w1;
            }
            int cnt = end - t; if (cnt > 64) cnt = 64;
            for (int j = 0; 4 * j < cnt; j++) {
                int e = 4 * j + g;
                int sq    = __shfl(s, e);
                float wq0 = __shfl(w0, e);
                float wq1 = __shfl(w1, e);
                if (e < cnt) {
                    const unsigned short* row = Hb + ((size_t)sq << 8);
                    uint4 q0 = *(const uint4*)(row + gl * 8);
                    uint4 q1 = *(const uint4*)(row + 128 + gl * 8);
                    acc8(acc0, wq0, q0);
                    acc8(acc1, wq1, q1);
                }
            }
        }
#pragma unroll
        for (int m = 1; m < 64; m <<= 1) { z0 += __shfl_xor(z0, m); z1 += __shfl_xor(z1, m); }
    }

    float inv0 = 1.f / (z0 + 1e-16f), inv1 = 1.f / (z1 + 1e-16f);
    // combine the 4 groups' partial accumulators
#pragma unroll
    for (int k = 0; k < 8; k++) {
        acc0[k] += __shfl_xor(acc0[k], 16); acc0[k] += __shfl_xor(acc0[k], 32);
        acc1[k] += __shfl_xor(acc1[k], 16); acc1[k] += __shfl_xor(acc1[k], 32);
    }

    // head mean + bias (channels gl*8 .. gl*8+8)
    float v[8];
    if (fx) {
        const float* bf = (const float*)bias + layer * 128 + gl * 8;
#pragma unroll
        for (int k = 0; k < 8; k++) v[k] = 0.5f * (acc0[k] * inv0 + acc1[k] * inv1) + bf[k];
    } else {
        const unsigned short* bh = (const unsigned short*)bias + layer * 128 + gl * 8;
        uint4 bv = *(const uint4*)bh;
        float bfv[8] = { bflo(bv.x), bfhi(bv.x), bflo(bv.y), bfhi(bv.y),
                         bflo(bv.z), bfhi(bv.z), bflo(bv.w), bfhi(bv.w) };
#pragma unroll
        for (int k = 0; k < 8; k++) v[k] = 0.5f * (acc0[k] * inv0 + acc1[k] * inv1) + bfv[k];
    }

    // L2 normalize over 128 channels (reduce within 16-lane group)
    float ss = 0.f;
#pragma unroll
    for (int k = 0; k < 8; k++) ss += v[k] * v[k];
#pragma unroll
    for (int m = 1; m < 16; m <<= 1) ss += __shfl_xor(ss, m);
    float inv = 1.f / fmaxf(sqrtf(ss), 1e-12f);

    if (lane < 16) {   // group 0 writes; channels gl*8..gl*8+8
        if (fx) {
            float* op = (float*)outp + (size_t)n * 128 + gl * 8;
            float4 o0 = { v[0] * inv, v[1] * inv, v[2] * inv, v[3] * inv };
            float4 o1 = { v[4] * inv, v[5] * inv, v[6] * inv, v[7] * inv };
            *(float4*)op = o0;
            *(float4*)(op + 4) = o1;
        } else {
            unsigned short* op = (unsigned short*)outp + (size_t)n * 128 + gl * 8;
            uint4 pk;
            pk.x = (unsigned int)f2bf(v[0] * inv) | ((unsigned int)f2bf(v[1] * inv) << 16);
            pk.y = (unsigned int)f2bf(v[2] * inv) | ((unsigned int)f2bf(v[3] * inv) << 16);
            pk.z = (unsigned int)f2bf(v[4] * inv) | ((unsigned int)f2bf(v[5] * inv) << 16);
            pk.w = (unsigned int)f2bf(v[6] * inv) | ((unsigned int)f2bf(v[7] * inv) << 16);
            *(uint4*)op = pk;
        }
    }
}

extern "C" void kernel_launch(void* const* d_in, const int* in_sizes, int n_in,
                              void* d_out, int out_size, void* d_ws, size_t ws_size,
                              hipStream_t stream) {
    const void* x    = d_in[0];               // [N,128] fp32 or bf16
    const int*  ei   = (const int*)d_in[1];   // [2,E] int32 or int64
    const void* W    = d_in[2];               // [2,128,256]
    const void* atts = d_in[3];               // [2,2,128]
    const void* attd = d_in[4];               // [2,2,128]
    const void* bias = d_in[5];               // [2,128]

    int N = in_sizes[0] / 128;
    int E = in_sizes[1] / 2;
    int EL = E + N;

    char* p = (char*)d_ws;
    auto alloc = [&](size_t bytes) -> char* {
        char* q = p; p += (bytes + 255) & ~(size_t)255; return q;
    };
    int* flags   = (int*)alloc(256);
    int* bsum    = (int*)alloc(2048 * 4);
    int* rowptr  = (int*)alloc((size_t)(N + 1) * 4);
    int* cursor  = (int*)alloc((size_t)N * 4);
    float* as_   = (float*)alloc((size_t)N * 2 * 4);
    float* ad_   = (float*)alloc((size_t)N * 2 * 4);
    unsigned short* wt = (unsigned short*)alloc(2 * 256 * 128 * 2);
    int* csr     = (int*)alloc((size_t)EL * 4);
    unsigned short* hbuf = (unsigned short*)alloc((size_t)N * 256 * 2);   // 25.6 MB, last

    k_probe_zero<<<(N + 255) / 256, 256, 0, stream>>>((const unsigned int*)x, ei, flags, cursor, N);
    k_count<<<(EL + 255) / 256, 256, 0, stream>>>(ei, E, N, flags, cursor);
    int nb = (N + 1023) / 1024;
    k_scan1<<<nb, 1024, 0, stream>>>(cursor, rowptr, bsum, N);
    k_scan2<<<1, 256, 0, stream>>>(bsum, nb);
    k_scan3<<<(N + 256) / 256, 256, 0, stream>>>(rowptr, bsum, cursor, N);
    k_scatter<<<(EL + 255) / 256, 256, 0, stream>>>(ei, E, N, flags, cursor, csr);
    k_transpose<<<256, 256, 0, stream>>>(W, wt, flags);

    int mtiles = (N + 15) / 16;
    for (int l = 0; l < 2; l++) {
        const void* xin = (l == 0) ? x : (const void*)d_out;  // layer 1 reads layer-0 output
        k_gemm_alpha<<<mtiles, 256, 0, stream>>>(xin, wt + l * 32768, atts, attd, l,
                                                 hbuf, as_, ad_, N, flags);
        k_aggregate<<<(N + 3) / 4, 256, 0, stream>>>(hbuf, as_, ad_, rowptr, csr, bias, l, flags,
                                                     d_out, N, EL);
    }
}